// Round 18
// baseline (410.606 us; speedup 1.0000x reference)
//
#include <hip/hip_runtime.h>
#include <hip/hip_fp16.h>
#include <stdint.h>

#define NPTS 400000
#define NVOX 281600
#define TPB  256
#define NBLK ((NPTS + TPB - 1) / TPB)
#define SCANB (NVOX / 256)       // 1100 exact
#define STRETCH 64
#define FBLK (NPTS / STRETCH)    // 6250 exact
#define SBLK2 1024
#define GRAMB 64                 // bn0gram blocks

typedef _Float16 h8  __attribute__((ext_vector_type(8)));
typedef _Float16 h4v __attribute__((ext_vector_type(4)));
typedef float    f4  __attribute__((ext_vector_type(4)));

// XLA-style binning: division folded to multiply-by-reciprocal in f32.
// DO NOT CHANGE: exactly matches the golden (round 6->7 proof).
__device__ __forceinline__ int bin3(const float* __restrict__ pt,
                                    int& bx, int& by, int& bz) {
  float x = pt[1], y = pt[2], z = pt[3];
  bx = (int)fminf(fmaxf(floorf(x * 5.0f), 0.f), 351.f);
  by = (int)fminf(fmaxf(floorf((y + 40.f) * 5.0f), 0.f), 399.f);
  bz = (int)fminf(fmaxf(floorf((z + 3.f) * 0.25f), 0.f), 0.f);
  return (((int)pt[0] + bz) * 400 + by) * 352 + bx;
}

__device__ __forceinline__ int mkfeat(const float* __restrict__ pt,
    const float* __restrict__ vcnt, const float* __restrict__ vsx,
    const float* __restrict__ vsy, const float* __restrict__ vsz,
    float* f) {
  int bx, by, bz;
  int v = bin3(pt, bx, by, bz);
  float x = pt[1], y = pt[2], z = pt[3];
  float n = fmaxf(vcnt[v], 1.f);
  f[0] = x;  f[1] = y;  f[2] = z;  f[3] = pt[4];
  f[4] = x - vsx[v] / n;
  f[5] = y - vsy[v] / n;
  f[6] = z - vsz[v] / n;
  f[7] = x - (0.2f * (float)bx + 0.1f);
  f[8] = y - (0.2f * (float)by - 39.9f);
  f[9] = z - (4.0f * (float)bz - 1.0f);
  return v;
}

// ---------------- prologue ----------------
__global__ __launch_bounds__(256) void voxsum(const float* __restrict__ pts,
    float* __restrict__ vcnt, float* __restrict__ vsx,
    float* __restrict__ vsy, float* __restrict__ vsz) {
  int p = blockIdx.x * TPB + threadIdx.x;
  if (p >= NPTS) return;
  const float* pt = pts + (size_t)p * 5;
  int bx, by, bz;
  int v = bin3(pt, bx, by, bz);
  atomicAdd(&vcnt[v], 1.f);
  atomicAdd(&vsx[v], pt[1]);
  atomicAdd(&vsy[v], pt[2]);
  atomicAdd(&vsz[v], pt[3]);
}

// ---- BN0 stats via 10x10 Gram: Σh = (Σf)·w_c, Σh² = w_cᵀ(Σ f fᵀ)w_c ----
__global__ __launch_bounds__(256) void bn0gram(const float* __restrict__ pts,
    const float* __restrict__ vcnt, const float* __restrict__ vsx,
    const float* __restrict__ vsy, const float* __restrict__ vsz,
    double* __restrict__ gpart) {
  __shared__ float sred[4][65];
  int t = threadIdx.x, wv = t >> 6, ln = t & 63;
  float s[10], G[55];
  #pragma unroll
  for (int i = 0; i < 10; ++i) s[i] = 0.f;
  #pragma unroll
  for (int k = 0; k < 55; ++k) G[k] = 0.f;

  for (int p = blockIdx.x * 256 + t; p < NPTS; p += gridDim.x * 256) {
    float f[10];
    mkfeat(pts + (size_t)p * 5, vcnt, vsx, vsy, vsz, f);
    #pragma unroll
    for (int i = 0; i < 10; ++i) s[i] += f[i];
    int k = 0;
    #pragma unroll
    for (int i = 0; i < 10; ++i) {
      #pragma unroll
      for (int j = i; j < 10; ++j) { G[k] = fmaf(f[i], f[j], G[k]); ++k; }
    }
  }
  #pragma unroll
  for (int i = 0; i < 10; ++i) {
    #pragma unroll
    for (int m = 1; m < 64; m <<= 1) s[i] += __shfl_xor(s[i], m, 64);
  }
  #pragma unroll
  for (int k = 0; k < 55; ++k) {
    #pragma unroll
    for (int m = 1; m < 64; m <<= 1) G[k] += __shfl_xor(G[k], m, 64);
  }
  if (ln == 0) {
    #pragma unroll
    for (int i = 0; i < 10; ++i) sred[wv][i] = s[i];
    #pragma unroll
    for (int k = 0; k < 55; ++k) sred[wv][10 + k] = G[k];
  }
  __syncthreads();
  if (t < 65) {
    gpart[(size_t)blockIdx.x * 65 + t] =
        (double)sred[0][t] + sred[1][t] + sred[2][t] + sred[3][t];
  }
}

__global__ void bnfold0g(const double* __restrict__ gpart,
                         const float* __restrict__ W0,
                         const float* __restrict__ g0, const float* __restrict__ b0,
                         float* __restrict__ sc, float* __restrict__ sh) {
  __shared__ double acc[65];
  int t = threadIdx.x;
  if (t < 65) {
    double a = 0;
    for (int b = 0; b < GRAMB; ++b) a += gpart[(size_t)b * 65 + t];
    acc[t] = a;
  }
  __syncthreads();
  if (t >= 64) return;
  double w[10];
  #pragma unroll
  for (int i = 0; i < 10; ++i) w[i] = (double)W0[i * 64 + t];
  double mu = 0;
  #pragma unroll
  for (int i = 0; i < 10; ++i) mu += acc[i] * w[i];
  mu /= (double)NPTS;
  double e2 = 0;
  int k = 0;
  #pragma unroll
  for (int i = 0; i < 10; ++i) {
    #pragma unroll
    for (int j = i; j < 10; ++j) {
      double term = acc[10 + k] * w[i] * w[j];
      e2 += (i == j) ? term : 2.0 * term;
      ++k;
    }
  }
  e2 /= (double)NPTS;
  double var = e2 - mu * mu;
  double sd = (double)g0[t] / sqrt(var + 1e-3);
  sc[t] = (float)sd;
  sh[t] = (float)((double)b0[t] - mu * sd);
}

__global__ void bnfold(const double* __restrict__ gs, const double* __restrict__ gq,
                       const float* __restrict__ gam, const float* __restrict__ bet,
                       float* __restrict__ sc, float* __restrict__ sh, int C) {
  int c = threadIdx.x;
  if (c >= C) return;
  double mu  = gs[c] / (double)NPTS;
  double var = gq[c] / (double)NPTS - mu * mu;
  double s = (double)gam[c] / sqrt(var + 1e-3);
  sc[c] = (float)s;
  sh[c] = (float)((double)bet[c] - mu * s);
}

// ---------------- counting sort ----------------
__global__ __launch_bounds__(256) void scan1(const float* __restrict__ vcnt,
    unsigned int* __restrict__ voxloc, unsigned int* __restrict__ bsum) {
  __shared__ unsigned int s[256];
  int t = threadIdx.x;
  int i = blockIdx.x * 256 + t;
  unsigned int val = (unsigned int)vcnt[i];
  s[t] = val;
  __syncthreads();
  for (int off = 1; off < 256; off <<= 1) {
    unsigned int add = (t >= off) ? s[t - off] : 0u;
    __syncthreads();
    s[t] += add;
    __syncthreads();
  }
  voxloc[i] = s[t] - val;
  if (t == 255) bsum[blockIdx.x] = s[t];
}

__global__ void scan2(const unsigned int* __restrict__ bsum,
                      unsigned int* __restrict__ bexc) {
  if (threadIdx.x != 0) return;
  unsigned int run = 0;
  for (int b = 0; b < SCANB; ++b) { bexc[b] = run; run += bsum[b]; }
}

// zero only rows that need it
__global__ __launch_bounds__(256) void prep(const float* __restrict__ vcnt,
    const unsigned int* __restrict__ voxloc, const unsigned int* __restrict__ bexc,
    float* __restrict__ vmax, float* __restrict__ outp) {
  int v = blockIdx.x * 256 + threadIdx.x;
  int n = (int)vcnt[v];
  f4 z = {0, 0, 0, 0};
  if (n == 0) {
    f4* o = (f4*)(outp + (size_t)v * 128);
    #pragma unroll
    for (int i = 0; i < 32; ++i) o[i] = z;
    return;
  }
  unsigned int vstart = voxloc[v] + bexc[v >> 8];
  bool interior = ((vstart & (STRETCH - 1)) + (unsigned)n) <= STRETCH;
  if (!interior) {
    f4* o = (f4*)(outp + (size_t)v * 128);
    #pragma unroll
    for (int i = 0; i < 32; ++i) o[i] = z;
    f4* m = (f4*)(vmax + (size_t)v * 64);
    #pragma unroll
    for (int i = 0; i < 16; ++i) m[i] = z;
  }
}

__global__ __launch_bounds__(256) void scatter(const float* __restrict__ pts,
    const unsigned int* __restrict__ voxloc, const unsigned int* __restrict__ bexc,
    unsigned int* __restrict__ cursor, unsigned int* __restrict__ plist,
    unsigned int* __restrict__ vsort) {
  int p = blockIdx.x * TPB + threadIdx.x;
  if (p >= NPTS) return;
  int bx, by, bz;
  int v = bin3(pts + (size_t)p * 5, bx, by, bz);
  unsigned int pos = voxloc[v] + bexc[v >> 8] + atomicAdd(&cursor[v], 1u);
  plist[pos] = (unsigned int)p;
  vsort[pos] = (unsigned int)v;
}

// ------ vmax0 over sorted stretches (+ pf0h byproduct, coalesced) ------
__global__ __launch_bounds__(256) void vmax0_stretch(const float* __restrict__ pts,
    const float* __restrict__ vcnt, const float* __restrict__ vsx,
    const float* __restrict__ vsy, const float* __restrict__ vsz,
    const unsigned int* __restrict__ voxloc, const unsigned int* __restrict__ bexc,
    const unsigned int* __restrict__ plist,
    const float* __restrict__ W0, const float* __restrict__ sc0,
    const float* __restrict__ sh0, float* __restrict__ vmax,
    _Float16* __restrict__ pf0h) {
  __shared__ float sf[STRETCH][12];
  __shared__ int   svid[STRETCH];
  __shared__ float pf[STRETCH][64];
  int t = threadIdx.x;
  unsigned int sbeg = blockIdx.x * STRETCH;

  if (t < STRETCH) {
    unsigned int pidx = plist[sbeg + t];
    svid[t] = mkfeat(pts + (size_t)pidx * 5, vcnt, vsx, vsy, vsz, &sf[t][0]);
  }
  __syncthreads();
  for (int idx = t; idx < STRETCH * 64; idx += TPB) {
    int pt_ = idx >> 6, k = idx & 63;
    float h = sf[pt_][0] * W0[k];
    #pragma unroll
    for (int i = 1; i < 10; ++i) h = fmaf(sf[pt_][i], W0[i * 64 + k], h);
    float val = fmaxf(fmaf(h, sc0[k], sh0[k]), 0.f);
    pf[pt_][k] = val;
    if (pf0h) pf0h[(size_t)(sbeg + pt_) * 64 + k] = (_Float16)val;
  }
  __syncthreads();

  if (t < 64) {
    int curv = -1; float curm = 0.f;
    for (int i = 0; i < STRETCH; ++i) {
      int v = svid[i];
      if (v != curv) {
        if (curv >= 0) {
          unsigned int vstart = voxloc[curv] + bexc[curv >> 8];
          unsigned int n = (unsigned int)vcnt[curv];
          if (vstart >= sbeg && vstart + n <= sbeg + STRETCH)
            vmax[(size_t)curv * 64 + t] = curm;
          else
            atomicMax((unsigned int*)&vmax[(size_t)curv * 64 + t],
                      __float_as_uint(curm));
        }
        curv = v;
        curm = pf[i][t];
      } else {
        curm = fmaxf(curm, pf[i][t]);
      }
    }
    if (curv >= 0) {
      unsigned int vstart = voxloc[curv] + bexc[curv >> 8];
      unsigned int n = (unsigned int)vcnt[curv];
      if (vstart >= sbeg && vstart + n <= sbeg + STRETCH)
        vmax[(size_t)curv * 64 + t] = curm;
      else
        atomicMax((unsigned int*)&vmax[(size_t)curv * 64 + t],
                  __float_as_uint(curm));
    }
  }
}

// ---------------- W1 -> fragment-ordered fp16 ----------------
__global__ __launch_bounds__(256) void wconv(const float* __restrict__ W1,
                                             _Float16* __restrict__ Wf) {
  int idx = blockIdx.x * 256 + threadIdx.x;
  if (idx >= 32 * 64 * 8) return;
  int j = idx & 7, l = (idx >> 3) & 63, f = idx >> 9;
  int ks = f & 3, ntile = f >> 2;
  int k = ks * 32 + ((j >> 2) * 16) + 4 * (l >> 4) + (j & 3);
  int n = ntile * 16 + (l & 15);
  Wf[idx] = (_Float16)W1[k * 128 + n];
}

// ---------------- MFMA layer-1: pf0h bulk-staged into LDS ----------------
__device__ __forceinline__ h8 lda(const _Float16* __restrict__ r, int k0) {
  h4v lo = *(const h4v*)(r + k0);
  h4v hi = *(const h4v*)(r + k0 + 16);
  h8 a;
  a[0] = lo[0]; a[1] = lo[1]; a[2] = lo[2]; a[3] = lo[3];
  a[4] = hi[0]; a[5] = hi[1]; a[6] = hi[2]; a[7] = hi[3];
  return a;
}

__device__ __forceinline__ void emit_tile(f4 C, int ptb, int ch,
    _Float16* __restrict__ h1o, float& sf_, float& qf_) {
  float v0 = C[0], v1 = C[1], v2 = C[2], v3 = C[3];
  h1o[(size_t)(ptb + 0) * 128 + ch] = (_Float16)v0;
  h1o[(size_t)(ptb + 1) * 128 + ch] = (_Float16)v1;
  h1o[(size_t)(ptb + 2) * 128 + ch] = (_Float16)v2;
  h1o[(size_t)(ptb + 3) * 128 + ch] = (_Float16)v3;
  sf_ += (v0 + v1) + (v2 + v3);
  qf_ = fmaf(v0, v0, fmaf(v1, v1, fmaf(v2, v2, fmaf(v3, v3, qf_))));
}

__global__ __launch_bounds__(256) void gemm1m(
    const unsigned int* __restrict__ vsort,
    const _Float16* __restrict__ pf0h, const float* __restrict__ vmax,
    const _Float16* __restrict__ Wf,
    double* __restrict__ gs, double* __restrict__ gq,
    _Float16* __restrict__ h1out) {
  __shared__ int svid[STRETCH];
  __shared__ __align__(16) _Float16 fh[64][140];   // 280B rows: <=2-way banks

  int t = threadIdx.x;
  int w = t >> 6, l = t & 63;
  int lm = l & 15, lg = l >> 4;

  const h8* wfv = (const h8*)Wf;
  h8 B00 = wfv[((w * 2 + 0) * 4 + 0) * 64 + l];
  h8 B01 = wfv[((w * 2 + 0) * 4 + 1) * 64 + l];
  h8 B02 = wfv[((w * 2 + 0) * 4 + 2) * 64 + l];
  h8 B03 = wfv[((w * 2 + 0) * 4 + 3) * 64 + l];
  h8 B10 = wfv[((w * 2 + 1) * 4 + 0) * 64 + l];
  h8 B11 = wfv[((w * 2 + 1) * 4 + 1) * 64 + l];
  h8 B12 = wfv[((w * 2 + 1) * 4 + 2) * 64 + l];
  h8 B13 = wfv[((w * 2 + 1) * 4 + 3) * 64 + l];

  double sd0 = 0, sd1 = 0, qd0 = 0, qd1 = 0;

  for (int tile = blockIdx.x; tile < FBLK; tile += gridDim.x) {
    unsigned int sbeg = tile * STRETCH;
    if (t < STRETCH) svid[t] = (int)vsort[sbeg + t];
    // coalesced bulk copy pf0h tile -> fh[p][0..63] (8B chunks; identical
    // values/rounding to the old in-kernel recompute)
    {
      const h4v* src = (const h4v*)(pf0h + (size_t)sbeg * 64);
      #pragma unroll
      for (int it = 0; it < 4; ++it) {
        int idx = it * TPB + t;            // 0..1023 over 64 pts x 16 chunks
        int p_ = idx >> 4, j = idx & 15;
        *(h4v*)(&fh[p_][j * 4]) = src[idx];
      }
    }
    __syncthreads();
    for (int idx = t; idx < STRETCH * 64; idx += TPB) {
      int p_ = idx >> 6, k = idx & 63;
      fh[p_][64 + k] = (_Float16)vmax[(size_t)svid[p_] * 64 + k];
    }
    __syncthreads();

    f4 C00 = {0,0,0,0}, C01 = {0,0,0,0}, C10 = {0,0,0,0}, C11 = {0,0,0,0};
    f4 C20 = {0,0,0,0}, C21 = {0,0,0,0}, C30 = {0,0,0,0}, C31 = {0,0,0,0};

    #define DO_MT(mt, CA, CB) {                                              \
      const _Float16* r = &fh[(mt) * 16 + lm][0];                            \
      h8 A0 = lda(r, 0 * 32 + 4 * lg);                                       \
      h8 A1 = lda(r, 1 * 32 + 4 * lg);                                       \
      h8 A2 = lda(r, 2 * 32 + 4 * lg);                                       \
      h8 A3 = lda(r, 3 * 32 + 4 * lg);                                       \
      CA = __builtin_amdgcn_mfma_f32_16x16x32_f16(A0, B00, CA, 0, 0, 0);     \
      CA = __builtin_amdgcn_mfma_f32_16x16x32_f16(A1, B01, CA, 0, 0, 0);     \
      CA = __builtin_amdgcn_mfma_f32_16x16x32_f16(A2, B02, CA, 0, 0, 0);     \
      CA = __builtin_amdgcn_mfma_f32_16x16x32_f16(A3, B03, CA, 0, 0, 0);     \
      CB = __builtin_amdgcn_mfma_f32_16x16x32_f16(A0, B10, CB, 0, 0, 0);     \
      CB = __builtin_amdgcn_mfma_f32_16x16x32_f16(A1, B11, CB, 0, 0, 0);     \
      CB = __builtin_amdgcn_mfma_f32_16x16x32_f16(A2, B12, CB, 0, 0, 0);     \
      CB = __builtin_amdgcn_mfma_f32_16x16x32_f16(A3, B13, CB, 0, 0, 0); }
    DO_MT(0, C00, C01)
    DO_MT(1, C10, C11)
    DO_MT(2, C20, C21)
    DO_MT(3, C30, C31)
    #undef DO_MT

    float s0f = 0, q0f = 0, s1f = 0, q1f = 0;
    int ch0 = w * 32 + lm, ch1 = w * 32 + 16 + lm;
    emit_tile(C00, sbeg + 0 * 16 + lg * 4, ch0, h1out, s0f, q0f);
    emit_tile(C01, sbeg + 0 * 16 + lg * 4, ch1, h1out, s1f, q1f);
    emit_tile(C10, sbeg + 1 * 16 + lg * 4, ch0, h1out, s0f, q0f);
    emit_tile(C11, sbeg + 1 * 16 + lg * 4, ch1, h1out, s1f, q1f);
    emit_tile(C20, sbeg + 2 * 16 + lg * 4, ch0, h1out, s0f, q0f);
    emit_tile(C21, sbeg + 2 * 16 + lg * 4, ch1, h1out, s1f, q1f);
    emit_tile(C30, sbeg + 3 * 16 + lg * 4, ch0, h1out, s0f, q0f);
    emit_tile(C31, sbeg + 3 * 16 + lg * 4, ch1, h1out, s1f, q1f);
    sd0 += (double)s0f; qd0 += (double)q0f;
    sd1 += (double)s1f; qd1 += (double)q1f;
    __syncthreads();
  }

  sd0 += __shfl_xor(sd0, 16, 64); sd0 += __shfl_xor(sd0, 32, 64);
  qd0 += __shfl_xor(qd0, 16, 64); qd0 += __shfl_xor(qd0, 32, 64);
  sd1 += __shfl_xor(sd1, 16, 64); sd1 += __shfl_xor(sd1, 32, 64);
  qd1 += __shfl_xor(qd1, 16, 64); qd1 += __shfl_xor(qd1, 32, 64);
  if (lg == 0) {
    atomicAdd(&gs[w * 32 + lm], sd0);
    atomicAdd(&gq[w * 32 + lm], qd0);
    atomicAdd(&gs[w * 32 + 16 + lm], sd1);
    atomicAdd(&gq[w * 32 + 16 + lm], qd1);
  }
}

// ---- fast final: wave-per-stretch, half2 channels, BN+ReLU, seg-max ----
__global__ __launch_bounds__(256) void final_cheap(
    const unsigned int* __restrict__ vsort,
    const unsigned int* __restrict__ voxloc, const unsigned int* __restrict__ bexc,
    const float* __restrict__ vcnt, const _Float16* __restrict__ h1,
    const float* __restrict__ sc1, const float* __restrict__ sh1,
    float* __restrict__ outp) {
  int t = threadIdx.x, w = t >> 6, l = t & 63;
  int s = blockIdx.x * 4 + w;
  if (s >= FBLK) return;
  unsigned int sbeg = (unsigned int)s * STRETCH;
  float2 sv = *(const float2*)(sc1 + 2 * l);
  float2 bv = *(const float2*)(sh1 + 2 * l);

  int curv = -1; float m0 = 0.f, m1 = 0.f;
  #define FLUSH()                                                            \
    { unsigned int vstart = voxloc[curv] + bexc[curv >> 8];                  \
      unsigned int n = (unsigned int)vcnt[curv];                             \
      if (vstart >= sbeg && vstart + n <= sbeg + STRETCH) {                  \
        *(float2*)(outp + (size_t)curv * 128 + 2 * l) = make_float2(m0, m1); \
      } else {                                                               \
        atomicMax((unsigned int*)&outp[(size_t)curv * 128 + 2 * l],          \
                  __float_as_uint(m0));                                      \
        atomicMax((unsigned int*)&outp[(size_t)curv * 128 + 2 * l + 1],      \
                  __float_as_uint(m1));                                      \
      } }
  for (int i = 0; i < STRETCH; ++i) {
    int v = (int)vsort[sbeg + i];
    __half2 hv = *(const __half2*)(h1 + (size_t)(sbeg + i) * 128 + 2 * l);
    float2 hf = __half22float2(hv);
    float v0 = fmaxf(fmaf(hf.x, sv.x, bv.x), 0.f);
    float v1 = fmaxf(fmaf(hf.y, sv.y, bv.y), 0.f);
    if (v != curv) {
      if (curv >= 0) FLUSH()
      curv = v; m0 = v0; m1 = v1;
    } else {
      m0 = fmaxf(m0, v0);
      m1 = fmaxf(m1, v1);
    }
  }
  if (curv >= 0) FLUSH()
  #undef FLUSH
}

// ---------------- fp32 fallback path (proven) ----------------
#define TILE_STAGE(sbeg_)                                                    \
  if (t < STRETCH) {                                                         \
    unsigned int pidx = plist[(sbeg_) + t];                                  \
    svid[t] = mkfeat(pts + (size_t)pidx * 5, vcnt, vsx, vsy, vsz, &sf[t][0]);\
  }                                                                          \
  __syncthreads();                                                           \
  for (int idx = t; idx < STRETCH * 64; idx += TPB) {                        \
    int pt_ = idx >> 6, k = idx & 63;                                        \
    float h = sf[pt_][0] * W0[k];                                            \
    _Pragma("unroll")                                                        \
    for (int i = 1; i < 10; ++i) h = fmaf(sf[pt_][i], W0[i * 64 + k], h);    \
    sfeat[pt_][k] = fmaxf(fmaf(h, sc0[k], sh0[k]), 0.f);                     \
  }                                                                          \
  for (int idx = t; idx < STRETCH * 64; idx += TPB) {                        \
    int pt_ = idx >> 6, k = idx & 63;                                        \
    sfeat[pt_][64 + k] = vmax[(size_t)svid[pt_] * 64 + k];                   \
  }                                                                          \
  __syncthreads();

#define TILE_GEMM()                                                          \
  const float* r0 = sfeat[pg * 8 + 0];                                       \
  const float* r1 = sfeat[pg * 8 + 1];                                       \
  const float* r2 = sfeat[pg * 8 + 2];                                       \
  const float* r3 = sfeat[pg * 8 + 3];                                       \
  const float* r4 = sfeat[pg * 8 + 4];                                       \
  const float* r5 = sfeat[pg * 8 + 5];                                       \
  const float* r6 = sfeat[pg * 8 + 6];                                       \
  const float* r7 = sfeat[pg * 8 + 7];                                       \
  float4 A0 = {0,0,0,0}, A1 = {0,0,0,0}, A2 = {0,0,0,0}, A3 = {0,0,0,0};     \
  float4 A4 = {0,0,0,0}, A5 = {0,0,0,0}, A6 = {0,0,0,0}, A7 = {0,0,0,0};     \
  _Pragma("unroll 8")                                                        \
  for (int k = 0; k < 128; ++k) {                                            \
    float4 w = *reinterpret_cast<const float4*>(W1 + (size_t)k * 128 + cb*4);\
    float p0 = r0[k], p1_ = r1[k], p2 = r2[k], p3 = r3[k];                   \
    float p4 = r4[k], p5 = r5[k], p6 = r6[k], p7 = r7[k];                    \
    A0.x = fmaf(p0, w.x, A0.x); A0.y = fmaf(p0, w.y, A0.y);                  \
    A0.z = fmaf(p0, w.z, A0.z); A0.w = fmaf(p0, w.w, A0.w);                  \
    A1.x = fmaf(p1_, w.x, A1.x); A1.y = fmaf(p1_, w.y, A1.y);                \
    A1.z = fmaf(p1_, w.z, A1.z); A1.w = fmaf(p1_, w.w, A1.w);                \
    A2.x = fmaf(p2, w.x, A2.x); A2.y = fmaf(p2, w.y, A2.y);                  \
    A2.z = fmaf(p2, w.z, A2.z); A2.w = fmaf(p2, w.w, A2.w);                  \
    A3.x = fmaf(p3, w.x, A3.x); A3.y = fmaf(p3, w.y, A3.y);                  \
    A3.z = fmaf(p3, w.z, A3.z); A3.w = fmaf(p3, w.w, A3.w);                  \
    A4.x = fmaf(p4, w.x, A4.x); A4.y = fmaf(p4, w.y, A4.y);                  \
    A4.z = fmaf(p4, w.z, A4.z); A4.w = fmaf(p4, w.w, A4.w);                  \
    A5.x = fmaf(p5, w.x, A5.x); A5.y = fmaf(p5, w.y, A5.y);                  \
    A5.z = fmaf(p5, w.z, A5.z); A5.w = fmaf(p5, w.w, A5.w);                  \
    A6.x = fmaf(p6, w.x, A6.x); A6.y = fmaf(p6, w.y, A6.y);                  \
    A6.z = fmaf(p6, w.z, A6.z); A6.w = fmaf(p6, w.w, A6.w);                  \
    A7.x = fmaf(p7, w.x, A7.x); A7.y = fmaf(p7, w.y, A7.y);                  \
    A7.z = fmaf(p7, w.z, A7.z); A7.w = fmaf(p7, w.w, A7.w);                  \
  }

__global__ __launch_bounds__(256) void gemm1s_f32(const float* __restrict__ pts,
    const float* __restrict__ vcnt, const float* __restrict__ vsx,
    const float* __restrict__ vsy, const float* __restrict__ vsz,
    const unsigned int* __restrict__ plist,
    const float* __restrict__ W0, const float* __restrict__ sc0,
    const float* __restrict__ sh0, const float* __restrict__ vmax,
    const float* __restrict__ W1,
    double* __restrict__ gs, double* __restrict__ gq) {
  union SM {
    struct { float sf[STRETCH][12]; int svid[STRETCH]; float sfeat[STRETCH][128]; } a;
    struct { double lsum[8 * 128]; double lsq[8 * 128]; } b;
  };
  __shared__ SM sm;
  auto& sf = sm.a.sf;
  auto& svid = sm.a.svid;
  auto& sfeat = sm.a.sfeat;

  int t = threadIdx.x;
  int pg = t >> 5, cb = t & 31;
  double sd0 = 0, sd1 = 0, sd2 = 0, sd3 = 0;
  double qd0 = 0, qd1 = 0, qd2 = 0, qd3 = 0;

  for (int tile = blockIdx.x; tile < FBLK; tile += gridDim.x) {
    unsigned int sbeg = tile * STRETCH;
    TILE_STAGE(sbeg)
    TILE_GEMM()
    sd0 += (double)A0.x + (double)A1.x + (double)A2.x + (double)A3.x
         + (double)A4.x + (double)A5.x + (double)A6.x + (double)A7.x;
    sd1 += (double)A0.y + (double)A1.y + (double)A2.y + (double)A3.y
         + (double)A4.y + (double)A5.y + (double)A6.y + (double)A7.y;
    sd2 += (double)A0.z + (double)A1.z + (double)A2.z + (double)A3.z
         + (double)A4.z + (double)A5.z + (double)A6.z + (double)A7.z;
    sd3 += (double)A0.w + (double)A1.w + (double)A2.w + (double)A3.w
         + (double)A4.w + (double)A5.w + (double)A6.w + (double)A7.w;
    qd0 += (double)A0.x*A0.x + (double)A1.x*A1.x + (double)A2.x*A2.x + (double)A3.x*A3.x
         + (double)A4.x*A4.x + (double)A5.x*A5.x + (double)A6.x*A6.x + (double)A7.x*A7.x;
    qd1 += (double)A0.y*A0.y + (double)A1.y*A1.y + (double)A2.y*A2.y + (double)A3.y*A3.y
         + (double)A4.y*A4.y + (double)A5.y*A5.y + (double)A6.y*A6.y + (double)A7.y*A7.y;
    qd2 += (double)A0.z*A0.z + (double)A1.z*A1.z + (double)A2.z*A2.z + (double)A3.z*A3.z
         + (double)A4.z*A4.z + (double)A5.z*A5.z + (double)A6.z*A6.z + (double)A7.z*A7.z;
    qd3 += (double)A0.w*A0.w + (double)A1.w*A1.w + (double)A2.w*A2.w + (double)A3.w*A3.w
         + (double)A4.w*A4.w + (double)A5.w*A5.w + (double)A6.w*A6.w + (double)A7.w*A7.w;
    __syncthreads();
  }

  int c = cb * 4;
  sm.b.lsum[pg * 128 + c + 0] = sd0;  sm.b.lsq[pg * 128 + c + 0] = qd0;
  sm.b.lsum[pg * 128 + c + 1] = sd1;  sm.b.lsq[pg * 128 + c + 1] = qd1;
  sm.b.lsum[pg * 128 + c + 2] = sd2;  sm.b.lsq[pg * 128 + c + 2] = qd2;
  sm.b.lsum[pg * 128 + c + 3] = sd3;  sm.b.lsq[pg * 128 + c + 3] = qd3;
  __syncthreads();
  if (t < 128) {
    double S = 0, Q = 0;
    #pragma unroll
    for (int j = 0; j < 8; ++j) { S += sm.b.lsum[j * 128 + t]; Q += sm.b.lsq[j * 128 + t]; }
    atomicAdd(&gs[t], S);
    atomicAdd(&gq[t], Q);
  }
}

__global__ __launch_bounds__(256) void final2(const float* __restrict__ pts,
    const float* __restrict__ vcnt, const float* __restrict__ vsx,
    const float* __restrict__ vsy, const float* __restrict__ vsz,
    const unsigned int* __restrict__ voxloc, const unsigned int* __restrict__ bexc,
    const unsigned int* __restrict__ plist,
    const float* __restrict__ W0, const float* __restrict__ sc0,
    const float* __restrict__ sh0, const float* __restrict__ vmax,
    const float* __restrict__ W1, const float* __restrict__ sc1,
    const float* __restrict__ sh1, float* __restrict__ outp) {
  __shared__ float sf[STRETCH][12];
  __shared__ int   svid[STRETCH];
  __shared__ float sfeat[STRETCH][128];

  int t = threadIdx.x;
  int pg = t >> 5, cb = t & 31;
  unsigned int sbeg = blockIdx.x * STRETCH;

  TILE_STAGE(sbeg)
  TILE_GEMM()
  __syncthreads();

  int c = cb * 4;
  float4 s1v = *reinterpret_cast<const float4*>(sc1 + c);
  float4 h1v = *reinterpret_cast<const float4*>(sh1 + c);
  #define BNST(Aj, j)                                                        \
    { float4 P;                                                              \
      P.x = fmaxf(fmaf(Aj.x, s1v.x, h1v.x), 0.f);                            \
      P.y = fmaxf(fmaf(Aj.y, s1v.y, h1v.y), 0.f);                            \
      P.z = fmaxf(fmaf(Aj.z, s1v.z, h1v.z), 0.f);                            \
      P.w = fmaxf(fmaf(Aj.w, s1v.w, h1v.w), 0.f);                            \
      *reinterpret_cast<float4*>(&sfeat[pg * 8 + j][c]) = P; }
  BNST(A0, 0) BNST(A1, 1) BNST(A2, 2) BNST(A3, 3)
  BNST(A4, 4) BNST(A5, 5) BNST(A6, 6) BNST(A7, 7)
  #undef BNST
  __syncthreads();

  if (t < 128) {
    int curv = -1; float curm = 0.f;
    for (int i = 0; i < STRETCH; ++i) {
      int v = svid[i];
      if (v != curv) {
        if (curv >= 0) {
          unsigned int vstart = voxloc[curv] + bexc[curv >> 8];
          unsigned int n = (unsigned int)vcnt[curv];
          if (vstart >= sbeg && vstart + n <= sbeg + STRETCH)
            outp[(size_t)curv * 128 + t] = curm;
          else
            atomicMax((unsigned int*)&outp[(size_t)curv * 128 + t],
                      __float_as_uint(curm));
        }
        curv = v;
        curm = sfeat[i][t];
      } else {
        curm = fmaxf(curm, sfeat[i][t]);
      }
    }
    if (curv >= 0) {
      unsigned int vstart = voxloc[curv] + bexc[curv >> 8];
      unsigned int n = (unsigned int)vcnt[curv];
      if (vstart >= sbeg && vstart + n <= sbeg + STRETCH)
        outp[(size_t)curv * 128 + t] = curm;
      else
        atomicMax((unsigned int*)&outp[(size_t)curv * 128 + t],
                  __float_as_uint(curm));
    }
  }
}

extern "C" void kernel_launch(void* const* d_in, const int* in_sizes, int n_in,
                              void* d_out, int out_size, void* d_ws, size_t ws_size,
                              hipStream_t stream) {
  const float* pts = (const float*)d_in[0];
  const float* W0  = (const float*)d_in[1];
  const float* g0  = (const float*)d_in[2];
  const float* b0  = (const float*)d_in[3];
  const float* W1  = (const float*)d_in[4];
  const float* g1  = (const float*)d_in[5];
  const float* b1  = (const float*)d_in[6];

  // ws layout: one contiguous zeroed region up front (single memset)
  char* base = (char*)d_ws;
  double* stats = (double*)base;                       // 3072 B (zeroed)
  float*  fold  = (float*)(base + 3072);               // 1536 B
  float*  vcnt  = (float*)(base + 4608);               // zeroed
  float*  vsx   = vcnt + NVOX;
  float*  vsy   = vsx + NVOX;
  float*  vsz   = vsy + NVOX;
  unsigned int* cursor = (unsigned int*)(vsz + NVOX);  // zeroed
  size_t zbytes = 4608 + (size_t)5 * NVOX * 4;
  unsigned int* voxloc = cursor + NVOX;
  unsigned int* plist  = voxloc + NVOX;
  unsigned int* vsort  = plist + NPTS;
  unsigned int* bsum   = vsort + NPTS;
  unsigned int* bexc   = bsum + SCANB;
  double* gpart = (double*)(bexc + SCANB);             // GRAMB*65 dbl (33KB)
  float* vmax = (float*)(gpart + GRAMB * 65);          // NVOX*64 f32 (72MB)
  _Float16* Wf = (_Float16*)(vmax + (size_t)NVOX * 64);// 32KB
  _Float16* pf0h = Wf + 32 * 64 * 8;                   // NPTS*64 fp16 (51MB)
  _Float16* h1 = pf0h + (size_t)NPTS * 64;             // NPTS*128 fp16 (102MB)
  size_t need_fast = (size_t)((char*)h1 - base) + (size_t)NPTS * 128 * sizeof(_Float16);
  bool fast = ws_size >= need_fast;

  double* s1 = stats + 128, *q1 = stats + 256;
  float* sc0 = fold,       *sh0 = fold + 64;
  float* sc1 = fold + 128, *sh1 = fold + 256;

  hipMemsetAsync(base, 0, zbytes, stream);

  voxsum<<<NBLK, TPB, 0, stream>>>(pts, vcnt, vsx, vsy, vsz);
  scan1<<<SCANB, 256, 0, stream>>>(vcnt, voxloc, bsum);
  scan2<<<1, 64, 0, stream>>>(bsum, bexc);
  prep<<<SCANB, 256, 0, stream>>>(vcnt, voxloc, bexc, vmax, (float*)d_out);
  scatter<<<NBLK, TPB, 0, stream>>>(pts, voxloc, bexc, cursor, plist, vsort);
  bn0gram<<<GRAMB, 256, 0, stream>>>(pts, vcnt, vsx, vsy, vsz, gpart);
  bnfold0g<<<1, 128, 0, stream>>>(gpart, W0, g0, b0, sc0, sh0);
  vmax0_stretch<<<FBLK, TPB, 0, stream>>>(pts, vcnt, vsx, vsy, vsz, voxloc, bexc,
                                          plist, W0, sc0, sh0, vmax,
                                          fast ? pf0h : nullptr);
  if (fast) {
    wconv<<<64, 256, 0, stream>>>(W1, Wf);
    gemm1m<<<SBLK2, TPB, 0, stream>>>(vsort, pf0h, vmax, Wf, s1, q1, h1);
    bnfold<<<1, 128, 0, stream>>>(s1, q1, g1, b1, sc1, sh1, 128);
    final_cheap<<<(FBLK + 3) / 4, 256, 0, stream>>>(vsort, voxloc, bexc, vcnt,
                                                    h1, sc1, sh1, (float*)d_out);
  } else {
    gemm1s_f32<<<SBLK2, TPB, 0, stream>>>(pts, vcnt, vsx, vsy, vsz, plist,
                                          W0, sc0, sh0, vmax, W1, s1, q1);
    bnfold<<<1, 128, 0, stream>>>(s1, q1, g1, b1, sc1, sh1, 128);
    final2<<<FBLK, TPB, 0, stream>>>(pts, vcnt, vsx, vsy, vsz, voxloc, bexc,
                                     plist, W0, sc0, sh0, vmax, W1, sc1, sh1,
                                     (float*)d_out);
  }
}

// Round 19
// 377.821 us; speedup vs baseline: 1.0868x; 1.0868x over previous
//
#include <hip/hip_runtime.h>
#include <hip/hip_fp16.h>
#include <stdint.h>

#define NPTS 400000
#define NVOX 281600
#define TPB  256
#define NBLK ((NPTS + TPB - 1) / TPB)
#define SCANB (NVOX / 256)       // 1100 exact
#define STRETCH 64
#define FBLK (NPTS / STRETCH)    // 6250 exact
#define SBLK2 1024
#define GRAMB 64                 // bn0gram blocks

typedef _Float16 h8  __attribute__((ext_vector_type(8)));
typedef _Float16 h4v __attribute__((ext_vector_type(4)));
typedef float    f4  __attribute__((ext_vector_type(4)));

// XLA-style binning: division folded to multiply-by-reciprocal in f32.
// DO NOT CHANGE: exactly matches the golden (round 6->7 proof).
__device__ __forceinline__ int bin3(const float* __restrict__ pt,
                                    int& bx, int& by, int& bz) {
  float x = pt[1], y = pt[2], z = pt[3];
  bx = (int)fminf(fmaxf(floorf(x * 5.0f), 0.f), 351.f);
  by = (int)fminf(fmaxf(floorf((y + 40.f) * 5.0f), 0.f), 399.f);
  bz = (int)fminf(fmaxf(floorf((z + 3.f) * 0.25f), 0.f), 0.f);
  return (((int)pt[0] + bz) * 400 + by) * 352 + bx;
}

__device__ __forceinline__ int mkfeat(const float* __restrict__ pt,
    const float* __restrict__ vcnt, const float* __restrict__ vsx,
    const float* __restrict__ vsy, const float* __restrict__ vsz,
    float* f) {
  int bx, by, bz;
  int v = bin3(pt, bx, by, bz);
  float x = pt[1], y = pt[2], z = pt[3];
  float n = fmaxf(vcnt[v], 1.f);
  f[0] = x;  f[1] = y;  f[2] = z;  f[3] = pt[4];
  f[4] = x - vsx[v] / n;
  f[5] = y - vsy[v] / n;
  f[6] = z - vsz[v] / n;
  f[7] = x - (0.2f * (float)bx + 0.1f);
  f[8] = y - (0.2f * (float)by - 39.9f);
  f[9] = z - (4.0f * (float)bz - 1.0f);
  return v;
}

// ---------------- prologue ----------------
__global__ __launch_bounds__(256) void voxsum(const float* __restrict__ pts,
    float* __restrict__ vcnt, float* __restrict__ vsx,
    float* __restrict__ vsy, float* __restrict__ vsz) {
  int p = blockIdx.x * TPB + threadIdx.x;
  if (p >= NPTS) return;
  const float* pt = pts + (size_t)p * 5;
  int bx, by, bz;
  int v = bin3(pt, bx, by, bz);
  atomicAdd(&vcnt[v], 1.f);
  atomicAdd(&vsx[v], pt[1]);
  atomicAdd(&vsy[v], pt[2]);
  atomicAdd(&vsz[v], pt[3]);
}

// ---- BN0 stats via 10x10 Gram: Σh = (Σf)·w_c, Σh² = w_cᵀ(Σ f fᵀ)w_c ----
__global__ __launch_bounds__(256) void bn0gram(const float* __restrict__ pts,
    const float* __restrict__ vcnt, const float* __restrict__ vsx,
    const float* __restrict__ vsy, const float* __restrict__ vsz,
    double* __restrict__ gpart) {
  __shared__ float sred[4][65];
  int t = threadIdx.x, wv = t >> 6, ln = t & 63;
  float s[10], G[55];
  #pragma unroll
  for (int i = 0; i < 10; ++i) s[i] = 0.f;
  #pragma unroll
  for (int k = 0; k < 55; ++k) G[k] = 0.f;

  for (int p = blockIdx.x * 256 + t; p < NPTS; p += gridDim.x * 256) {
    float f[10];
    mkfeat(pts + (size_t)p * 5, vcnt, vsx, vsy, vsz, f);
    #pragma unroll
    for (int i = 0; i < 10; ++i) s[i] += f[i];
    int k = 0;
    #pragma unroll
    for (int i = 0; i < 10; ++i) {
      #pragma unroll
      for (int j = i; j < 10; ++j) { G[k] = fmaf(f[i], f[j], G[k]); ++k; }
    }
  }
  #pragma unroll
  for (int i = 0; i < 10; ++i) {
    #pragma unroll
    for (int m = 1; m < 64; m <<= 1) s[i] += __shfl_xor(s[i], m, 64);
  }
  #pragma unroll
  for (int k = 0; k < 55; ++k) {
    #pragma unroll
    for (int m = 1; m < 64; m <<= 1) G[k] += __shfl_xor(G[k], m, 64);
  }
  if (ln == 0) {
    #pragma unroll
    for (int i = 0; i < 10; ++i) sred[wv][i] = s[i];
    #pragma unroll
    for (int k = 0; k < 55; ++k) sred[wv][10 + k] = G[k];
  }
  __syncthreads();
  if (t < 65) {
    gpart[(size_t)blockIdx.x * 65 + t] =
        (double)sred[0][t] + sred[1][t] + sred[2][t] + sred[3][t];
  }
}

__global__ void bnfold0g(const double* __restrict__ gpart,
                         const float* __restrict__ W0,
                         const float* __restrict__ g0, const float* __restrict__ b0,
                         float* __restrict__ sc, float* __restrict__ sh) {
  __shared__ double acc[65];
  int t = threadIdx.x;
  if (t < 65) {
    double a = 0;
    for (int b = 0; b < GRAMB; ++b) a += gpart[(size_t)b * 65 + t];
    acc[t] = a;
  }
  __syncthreads();
  if (t >= 64) return;
  double w[10];
  #pragma unroll
  for (int i = 0; i < 10; ++i) w[i] = (double)W0[i * 64 + t];
  double mu = 0;
  #pragma unroll
  for (int i = 0; i < 10; ++i) mu += acc[i] * w[i];
  mu /= (double)NPTS;
  double e2 = 0;
  int k = 0;
  #pragma unroll
  for (int i = 0; i < 10; ++i) {
    #pragma unroll
    for (int j = i; j < 10; ++j) {
      double term = acc[10 + k] * w[i] * w[j];
      e2 += (i == j) ? term : 2.0 * term;
      ++k;
    }
  }
  e2 /= (double)NPTS;
  double var = e2 - mu * mu;
  double sd = (double)g0[t] / sqrt(var + 1e-3);
  sc[t] = (float)sd;
  sh[t] = (float)((double)b0[t] - mu * sd);
}

__global__ void bnfold(const double* __restrict__ gs, const double* __restrict__ gq,
                       const float* __restrict__ gam, const float* __restrict__ bet,
                       float* __restrict__ sc, float* __restrict__ sh, int C) {
  int c = threadIdx.x;
  if (c >= C) return;
  double mu  = gs[c] / (double)NPTS;
  double var = gq[c] / (double)NPTS - mu * mu;
  double s = (double)gam[c] / sqrt(var + 1e-3);
  sc[c] = (float)s;
  sh[c] = (float)((double)bet[c] - mu * s);
}

// ---------------- counting sort ----------------
__global__ __launch_bounds__(256) void scan1(const float* __restrict__ vcnt,
    unsigned int* __restrict__ voxloc, unsigned int* __restrict__ bsum) {
  __shared__ unsigned int s[256];
  int t = threadIdx.x;
  int i = blockIdx.x * 256 + t;
  unsigned int val = (unsigned int)vcnt[i];
  s[t] = val;
  __syncthreads();
  for (int off = 1; off < 256; off <<= 1) {
    unsigned int add = (t >= off) ? s[t - off] : 0u;
    __syncthreads();
    s[t] += add;
    __syncthreads();
  }
  voxloc[i] = s[t] - val;
  if (t == 255) bsum[blockIdx.x] = s[t];
}

__global__ void scan2(const unsigned int* __restrict__ bsum,
                      unsigned int* __restrict__ bexc) {
  if (threadIdx.x != 0) return;
  unsigned int run = 0;
  for (int b = 0; b < SCANB; ++b) { bexc[b] = run; run += bsum[b]; }
}

// zero only rows that need it
__global__ __launch_bounds__(256) void prep(const float* __restrict__ vcnt,
    const unsigned int* __restrict__ voxloc, const unsigned int* __restrict__ bexc,
    float* __restrict__ vmax, float* __restrict__ outp) {
  int v = blockIdx.x * 256 + threadIdx.x;
  int n = (int)vcnt[v];
  f4 z = {0, 0, 0, 0};
  if (n == 0) {
    f4* o = (f4*)(outp + (size_t)v * 128);
    #pragma unroll
    for (int i = 0; i < 32; ++i) o[i] = z;
    return;
  }
  unsigned int vstart = voxloc[v] + bexc[v >> 8];
  bool interior = ((vstart & (STRETCH - 1)) + (unsigned)n) <= STRETCH;
  if (!interior) {
    f4* o = (f4*)(outp + (size_t)v * 128);
    #pragma unroll
    for (int i = 0; i < 32; ++i) o[i] = z;
    f4* m = (f4*)(vmax + (size_t)v * 64);
    #pragma unroll
    for (int i = 0; i < 16; ++i) m[i] = z;
  }
}

__global__ __launch_bounds__(256) void scatter(const float* __restrict__ pts,
    const unsigned int* __restrict__ voxloc, const unsigned int* __restrict__ bexc,
    unsigned int* __restrict__ cursor, unsigned int* __restrict__ plist,
    unsigned int* __restrict__ vsort) {
  int p = blockIdx.x * TPB + threadIdx.x;
  if (p >= NPTS) return;
  int bx, by, bz;
  int v = bin3(pts + (size_t)p * 5, bx, by, bz);
  unsigned int pos = voxloc[v] + bexc[v >> 8] + atomicAdd(&cursor[v], 1u);
  plist[pos] = (unsigned int)p;
  vsort[pos] = (unsigned int)v;
}

// ---------------- vmax0 over sorted stretches (R17-proven) ----------------
__global__ __launch_bounds__(256) void vmax0_stretch(const float* __restrict__ pts,
    const float* __restrict__ vcnt, const float* __restrict__ vsx,
    const float* __restrict__ vsy, const float* __restrict__ vsz,
    const unsigned int* __restrict__ voxloc, const unsigned int* __restrict__ bexc,
    const unsigned int* __restrict__ plist,
    const float* __restrict__ W0, const float* __restrict__ sc0,
    const float* __restrict__ sh0, float* __restrict__ vmax) {
  __shared__ float sf[STRETCH][12];
  __shared__ int   svid[STRETCH];
  __shared__ float pf[STRETCH][64];
  int t = threadIdx.x;
  unsigned int sbeg = blockIdx.x * STRETCH;

  if (t < STRETCH) {
    unsigned int pidx = plist[sbeg + t];
    svid[t] = mkfeat(pts + (size_t)pidx * 5, vcnt, vsx, vsy, vsz, &sf[t][0]);
  }
  __syncthreads();
  for (int idx = t; idx < STRETCH * 64; idx += TPB) {
    int pt_ = idx >> 6, k = idx & 63;
    float h = sf[pt_][0] * W0[k];
    #pragma unroll
    for (int i = 1; i < 10; ++i) h = fmaf(sf[pt_][i], W0[i * 64 + k], h);
    pf[pt_][k] = fmaxf(fmaf(h, sc0[k], sh0[k]), 0.f);
  }
  __syncthreads();

  if (t < 64) {
    int curv = -1; float curm = 0.f;
    for (int i = 0; i < STRETCH; ++i) {
      int v = svid[i];
      if (v != curv) {
        if (curv >= 0) {
          unsigned int vstart = voxloc[curv] + bexc[curv >> 8];
          unsigned int n = (unsigned int)vcnt[curv];
          if (vstart >= sbeg && vstart + n <= sbeg + STRETCH)
            vmax[(size_t)curv * 64 + t] = curm;
          else
            atomicMax((unsigned int*)&vmax[(size_t)curv * 64 + t],
                      __float_as_uint(curm));
        }
        curv = v;
        curm = pf[i][t];
      } else {
        curm = fmaxf(curm, pf[i][t]);
      }
    }
    if (curv >= 0) {
      unsigned int vstart = voxloc[curv] + bexc[curv >> 8];
      unsigned int n = (unsigned int)vcnt[curv];
      if (vstart >= sbeg && vstart + n <= sbeg + STRETCH)
        vmax[(size_t)curv * 64 + t] = curm;
      else
        atomicMax((unsigned int*)&vmax[(size_t)curv * 64 + t],
                  __float_as_uint(curm));
    }
  }
}

// ---------------- W1 -> fragment-ordered fp16 ----------------
__global__ __launch_bounds__(256) void wconv(const float* __restrict__ W1,
                                             _Float16* __restrict__ Wf) {
  int idx = blockIdx.x * 256 + threadIdx.x;
  if (idx >= 32 * 64 * 8) return;
  int j = idx & 7, l = (idx >> 3) & 63, f = idx >> 9;
  int ks = f & 3, ntile = f >> 2;
  int k = ks * 32 + ((j >> 2) * 16) + 4 * (l >> 4) + (j & 3);
  int n = ntile * 16 + (l & 15);
  Wf[idx] = (_Float16)W1[k * 128 + n];
}

// ---------------- MFMA layer-1 (R17-proven LDS-staged form) ----------------
__device__ __forceinline__ h8 lda(const _Float16* __restrict__ r, int k0) {
  h4v lo = *(const h4v*)(r + k0);
  h4v hi = *(const h4v*)(r + k0 + 16);
  h8 a;
  a[0] = lo[0]; a[1] = lo[1]; a[2] = lo[2]; a[3] = lo[3];
  a[4] = hi[0]; a[5] = hi[1]; a[6] = hi[2]; a[7] = hi[3];
  return a;
}

__device__ __forceinline__ void emit_tile(f4 C, int ptb, int ch,
    _Float16* __restrict__ h1o, float& sf_, float& qf_) {
  float v0 = C[0], v1 = C[1], v2 = C[2], v3 = C[3];
  h1o[(size_t)(ptb + 0) * 128 + ch] = (_Float16)v0;
  h1o[(size_t)(ptb + 1) * 128 + ch] = (_Float16)v1;
  h1o[(size_t)(ptb + 2) * 128 + ch] = (_Float16)v2;
  h1o[(size_t)(ptb + 3) * 128 + ch] = (_Float16)v3;
  sf_ += (v0 + v1) + (v2 + v3);
  qf_ = fmaf(v0, v0, fmaf(v1, v1, fmaf(v2, v2, fmaf(v3, v3, qf_))));
}

__global__ __launch_bounds__(256) void gemm1m(const float* __restrict__ pts,
    const float* __restrict__ vcnt, const float* __restrict__ vsx,
    const float* __restrict__ vsy, const float* __restrict__ vsz,
    const unsigned int* __restrict__ plist,
    const float* __restrict__ W0, const float* __restrict__ sc0,
    const float* __restrict__ sh0, const float* __restrict__ vmax,
    const _Float16* __restrict__ Wf,
    double* __restrict__ gs, double* __restrict__ gq,
    _Float16* __restrict__ h1out) {
  __shared__ float sf[STRETCH][12];
  __shared__ int   svid[STRETCH];
  __shared__ __align__(16) _Float16 fh[64][140];   // 280B rows: <=2-way banks

  int t = threadIdx.x;
  int w = t >> 6, l = t & 63;
  int lm = l & 15, lg = l >> 4;

  const h8* wfv = (const h8*)Wf;
  h8 B00 = wfv[((w * 2 + 0) * 4 + 0) * 64 + l];
  h8 B01 = wfv[((w * 2 + 0) * 4 + 1) * 64 + l];
  h8 B02 = wfv[((w * 2 + 0) * 4 + 2) * 64 + l];
  h8 B03 = wfv[((w * 2 + 0) * 4 + 3) * 64 + l];
  h8 B10 = wfv[((w * 2 + 1) * 4 + 0) * 64 + l];
  h8 B11 = wfv[((w * 2 + 1) * 4 + 1) * 64 + l];
  h8 B12 = wfv[((w * 2 + 1) * 4 + 2) * 64 + l];
  h8 B13 = wfv[((w * 2 + 1) * 4 + 3) * 64 + l];

  double sd0 = 0, sd1 = 0, qd0 = 0, qd1 = 0;

  for (int tile = blockIdx.x; tile < FBLK; tile += gridDim.x) {
    unsigned int sbeg = tile * STRETCH;
    if (t < STRETCH) {
      unsigned int pidx = plist[sbeg + t];
      svid[t] = mkfeat(pts + (size_t)pidx * 5, vcnt, vsx, vsy, vsz, &sf[t][0]);
    }
    __syncthreads();
    for (int idx = t; idx < STRETCH * 64; idx += TPB) {
      int p_ = idx >> 6, k = idx & 63;
      float h = sf[p_][0] * W0[k];
      #pragma unroll
      for (int i = 1; i < 10; ++i) h = fmaf(sf[p_][i], W0[i * 64 + k], h);
      fh[p_][k] = (_Float16)fmaxf(fmaf(h, sc0[k], sh0[k]), 0.f);
    }
    for (int idx = t; idx < STRETCH * 64; idx += TPB) {
      int p_ = idx >> 6, k = idx & 63;
      fh[p_][64 + k] = (_Float16)vmax[(size_t)svid[p_] * 64 + k];
    }
    __syncthreads();

    f4 C00 = {0,0,0,0}, C01 = {0,0,0,0}, C10 = {0,0,0,0}, C11 = {0,0,0,0};
    f4 C20 = {0,0,0,0}, C21 = {0,0,0,0}, C30 = {0,0,0,0}, C31 = {0,0,0,0};

    #define DO_MT(mt, CA, CB) {                                              \
      const _Float16* r = &fh[(mt) * 16 + lm][0];                            \
      h8 A0 = lda(r, 0 * 32 + 4 * lg);                                       \
      h8 A1 = lda(r, 1 * 32 + 4 * lg);                                       \
      h8 A2 = lda(r, 2 * 32 + 4 * lg);                                       \
      h8 A3 = lda(r, 3 * 32 + 4 * lg);                                       \
      CA = __builtin_amdgcn_mfma_f32_16x16x32_f16(A0, B00, CA, 0, 0, 0);     \
      CA = __builtin_amdgcn_mfma_f32_16x16x32_f16(A1, B01, CA, 0, 0, 0);     \
      CA = __builtin_amdgcn_mfma_f32_16x16x32_f16(A2, B02, CA, 0, 0, 0);     \
      CA = __builtin_amdgcn_mfma_f32_16x16x32_f16(A3, B03, CA, 0, 0, 0);     \
      CB = __builtin_amdgcn_mfma_f32_16x16x32_f16(A0, B10, CB, 0, 0, 0);     \
      CB = __builtin_amdgcn_mfma_f32_16x16x32_f16(A1, B11, CB, 0, 0, 0);     \
      CB = __builtin_amdgcn_mfma_f32_16x16x32_f16(A2, B12, CB, 0, 0, 0);     \
      CB = __builtin_amdgcn_mfma_f32_16x16x32_f16(A3, B13, CB, 0, 0, 0); }
    DO_MT(0, C00, C01)
    DO_MT(1, C10, C11)
    DO_MT(2, C20, C21)
    DO_MT(3, C30, C31)
    #undef DO_MT

    float s0f = 0, q0f = 0, s1f = 0, q1f = 0;
    int ch0 = w * 32 + lm, ch1 = w * 32 + 16 + lm;
    emit_tile(C00, sbeg + 0 * 16 + lg * 4, ch0, h1out, s0f, q0f);
    emit_tile(C01, sbeg + 0 * 16 + lg * 4, ch1, h1out, s1f, q1f);
    emit_tile(C10, sbeg + 1 * 16 + lg * 4, ch0, h1out, s0f, q0f);
    emit_tile(C11, sbeg + 1 * 16 + lg * 4, ch1, h1out, s1f, q1f);
    emit_tile(C20, sbeg + 2 * 16 + lg * 4, ch0, h1out, s0f, q0f);
    emit_tile(C21, sbeg + 2 * 16 + lg * 4, ch1, h1out, s1f, q1f);
    emit_tile(C30, sbeg + 3 * 16 + lg * 4, ch0, h1out, s0f, q0f);
    emit_tile(C31, sbeg + 3 * 16 + lg * 4, ch1, h1out, s1f, q1f);
    sd0 += (double)s0f; qd0 += (double)q0f;
    sd1 += (double)s1f; qd1 += (double)q1f;
    __syncthreads();
  }

  sd0 += __shfl_xor(sd0, 16, 64); sd0 += __shfl_xor(sd0, 32, 64);
  qd0 += __shfl_xor(qd0, 16, 64); qd0 += __shfl_xor(qd0, 32, 64);
  sd1 += __shfl_xor(sd1, 16, 64); sd1 += __shfl_xor(sd1, 32, 64);
  qd1 += __shfl_xor(qd1, 16, 64); qd1 += __shfl_xor(qd1, 32, 64);
  if (lg == 0) {
    atomicAdd(&gs[w * 32 + lm], sd0);
    atomicAdd(&gq[w * 32 + lm], qd0);
    atomicAdd(&gs[w * 32 + 16 + lm], sd1);
    atomicAdd(&gq[w * 32 + 16 + lm], qd1);
  }
}

// ---- fast final: wave-per-stretch, 8-deep batched loads for MLP ----
__global__ __launch_bounds__(256) void final_cheap(
    const unsigned int* __restrict__ vsort,
    const unsigned int* __restrict__ voxloc, const unsigned int* __restrict__ bexc,
    const float* __restrict__ vcnt, const _Float16* __restrict__ h1,
    const float* __restrict__ sc1, const float* __restrict__ sh1,
    float* __restrict__ outp) {
  int t = threadIdx.x, w = t >> 6, l = t & 63;
  int s = blockIdx.x * 4 + w;
  if (s >= FBLK) return;
  unsigned int sbeg = (unsigned int)s * STRETCH;
  float2 sv = *(const float2*)(sc1 + 2 * l);
  float2 bv = *(const float2*)(sh1 + 2 * l);

  int curv = -1; float m0 = 0.f, m1 = 0.f;
  #define FLUSH()                                                            \
    { unsigned int vstart = voxloc[curv] + bexc[curv >> 8];                  \
      unsigned int n = (unsigned int)vcnt[curv];                             \
      if (vstart >= sbeg && vstart + n <= sbeg + STRETCH) {                  \
        *(float2*)(outp + (size_t)curv * 128 + 2 * l) = make_float2(m0, m1); \
      } else {                                                               \
        atomicMax((unsigned int*)&outp[(size_t)curv * 128 + 2 * l],          \
                  __float_as_uint(m0));                                      \
        atomicMax((unsigned int*)&outp[(size_t)curv * 128 + 2 * l + 1],      \
                  __float_as_uint(m1));                                      \
      } }
  for (int ib = 0; ib < STRETCH / 8; ++ib) {
    // batch-issue 8 independent h1 loads + 8 vsort loads (8x MLP)
    __half2 hv0 = *(const __half2*)(h1 + (size_t)(sbeg + ib * 8 + 0) * 128 + 2 * l);
    __half2 hv1 = *(const __half2*)(h1 + (size_t)(sbeg + ib * 8 + 1) * 128 + 2 * l);
    __half2 hv2 = *(const __half2*)(h1 + (size_t)(sbeg + ib * 8 + 2) * 128 + 2 * l);
    __half2 hv3 = *(const __half2*)(h1 + (size_t)(sbeg + ib * 8 + 3) * 128 + 2 * l);
    __half2 hv4 = *(const __half2*)(h1 + (size_t)(sbeg + ib * 8 + 4) * 128 + 2 * l);
    __half2 hv5 = *(const __half2*)(h1 + (size_t)(sbeg + ib * 8 + 5) * 128 + 2 * l);
    __half2 hv6 = *(const __half2*)(h1 + (size_t)(sbeg + ib * 8 + 6) * 128 + 2 * l);
    __half2 hv7 = *(const __half2*)(h1 + (size_t)(sbeg + ib * 8 + 7) * 128 + 2 * l);
    uint4 vq0 = *(const uint4*)(vsort + sbeg + ib * 8);
    uint4 vq1 = *(const uint4*)(vsort + sbeg + ib * 8 + 4);
    int vv[8] = {(int)vq0.x, (int)vq0.y, (int)vq0.z, (int)vq0.w,
                 (int)vq1.x, (int)vq1.y, (int)vq1.z, (int)vq1.w};
    __half2 hh[8] = {hv0, hv1, hv2, hv3, hv4, hv5, hv6, hv7};
    #pragma unroll
    for (int j = 0; j < 8; ++j) {
      float2 hf = __half22float2(hh[j]);
      float v0 = fmaxf(fmaf(hf.x, sv.x, bv.x), 0.f);
      float v1 = fmaxf(fmaf(hf.y, sv.y, bv.y), 0.f);
      int v = vv[j];
      if (v != curv) {
        if (curv >= 0) FLUSH()
        curv = v; m0 = v0; m1 = v1;
      } else {
        m0 = fmaxf(m0, v0);
        m1 = fmaxf(m1, v1);
      }
    }
  }
  if (curv >= 0) FLUSH()
  #undef FLUSH
}

// ---------------- fp32 fallback path (proven) ----------------
#define TILE_STAGE(sbeg_)                                                    \
  if (t < STRETCH) {                                                         \
    unsigned int pidx = plist[(sbeg_) + t];                                  \
    svid[t] = mkfeat(pts + (size_t)pidx * 5, vcnt, vsx, vsy, vsz, &sf[t][0]);\
  }                                                                          \
  __syncthreads();                                                           \
  for (int idx = t; idx < STRETCH * 64; idx += TPB) {                        \
    int pt_ = idx >> 6, k = idx & 63;                                        \
    float h = sf[pt_][0] * W0[k];                                            \
    _Pragma("unroll")                                                        \
    for (int i = 1; i < 10; ++i) h = fmaf(sf[pt_][i], W0[i * 64 + k], h);    \
    sfeat[pt_][k] = fmaxf(fmaf(h, sc0[k], sh0[k]), 0.f);                     \
  }                                                                          \
  for (int idx = t; idx < STRETCH * 64; idx += TPB) {                        \
    int pt_ = idx >> 6, k = idx & 63;                                        \
    sfeat[pt_][64 + k] = vmax[(size_t)svid[pt_] * 64 + k];                   \
  }                                                                          \
  __syncthreads();

#define TILE_GEMM()                                                          \
  const float* r0 = sfeat[pg * 8 + 0];                                       \
  const float* r1 = sfeat[pg * 8 + 1];                                       \
  const float* r2 = sfeat[pg * 8 + 2];                                       \
  const float* r3 = sfeat[pg * 8 + 3];                                       \
  const float* r4 = sfeat[pg * 8 + 4];                                       \
  const float* r5 = sfeat[pg * 8 + 5];                                       \
  const float* r6 = sfeat[pg * 8 + 6];                                       \
  const float* r7 = sfeat[pg * 8 + 7];                                       \
  float4 A0 = {0,0,0,0}, A1 = {0,0,0,0}, A2 = {0,0,0,0}, A3 = {0,0,0,0};     \
  float4 A4 = {0,0,0,0}, A5 = {0,0,0,0}, A6 = {0,0,0,0}, A7 = {0,0,0,0};     \
  _Pragma("unroll 8")                                                        \
  for (int k = 0; k < 128; ++k) {                                            \
    float4 w = *reinterpret_cast<const float4*>(W1 + (size_t)k * 128 + cb*4);\
    float p0 = r0[k], p1_ = r1[k], p2 = r2[k], p3 = r3[k];                   \
    float p4 = r4[k], p5 = r5[k], p6 = r6[k], p7 = r7[k];                    \
    A0.x = fmaf(p0, w.x, A0.x); A0.y = fmaf(p0, w.y, A0.y);                  \
    A0.z = fmaf(p0, w.z, A0.z); A0.w = fmaf(p0, w.w, A0.w);                  \
    A1.x = fmaf(p1_, w.x, A1.x); A1.y = fmaf(p1_, w.y, A1.y);                \
    A1.z = fmaf(p1_, w.z, A1.z); A1.w = fmaf(p1_, w.w, A1.w);                \
    A2.x = fmaf(p2, w.x, A2.x); A2.y = fmaf(p2, w.y, A2.y);                  \
    A2.z = fmaf(p2, w.z, A2.z); A2.w = fmaf(p2, w.w, A2.w);                  \
    A3.x = fmaf(p3, w.x, A3.x); A3.y = fmaf(p3, w.y, A3.y);                  \
    A3.z = fmaf(p3, w.z, A3.z); A3.w = fmaf(p3, w.w, A3.w);                  \
    A4.x = fmaf(p4, w.x, A4.x); A4.y = fmaf(p4, w.y, A4.y);                  \
    A4.z = fmaf(p4, w.z, A4.z); A4.w = fmaf(p4, w.w, A4.w);                  \
    A5.x = fmaf(p5, w.x, A5.x); A5.y = fmaf(p5, w.y, A5.y);                  \
    A5.z = fmaf(p5, w.z, A5.z); A5.w = fmaf(p5, w.w, A5.w);                  \
    A6.x = fmaf(p6, w.x, A6.x); A6.y = fmaf(p6, w.y, A6.y);                  \
    A6.z = fmaf(p6, w.z, A6.z); A6.w = fmaf(p6, w.w, A6.w);                  \
    A7.x = fmaf(p7, w.x, A7.x); A7.y = fmaf(p7, w.y, A7.y);                  \
    A7.z = fmaf(p7, w.z, A7.z); A7.w = fmaf(p7, w.w, A7.w);                  \
  }

__global__ __launch_bounds__(256) void gemm1s_f32(const float* __restrict__ pts,
    const float* __restrict__ vcnt, const float* __restrict__ vsx,
    const float* __restrict__ vsy, const float* __restrict__ vsz,
    const unsigned int* __restrict__ plist,
    const float* __restrict__ W0, const float* __restrict__ sc0,
    const float* __restrict__ sh0, const float* __restrict__ vmax,
    const float* __restrict__ W1,
    double* __restrict__ gs, double* __restrict__ gq) {
  union SM {
    struct { float sf[STRETCH][12]; int svid[STRETCH]; float sfeat[STRETCH][128]; } a;
    struct { double lsum[8 * 128]; double lsq[8 * 128]; } b;
  };
  __shared__ SM sm;
  auto& sf = sm.a.sf;
  auto& svid = sm.a.svid;
  auto& sfeat = sm.a.sfeat;

  int t = threadIdx.x;
  int pg = t >> 5, cb = t & 31;
  double sd0 = 0, sd1 = 0, sd2 = 0, sd3 = 0;
  double qd0 = 0, qd1 = 0, qd2 = 0, qd3 = 0;

  for (int tile = blockIdx.x; tile < FBLK; tile += gridDim.x) {
    unsigned int sbeg = tile * STRETCH;
    TILE_STAGE(sbeg)
    TILE_GEMM()
    sd0 += (double)A0.x + (double)A1.x + (double)A2.x + (double)A3.x
         + (double)A4.x + (double)A5.x + (double)A6.x + (double)A7.x;
    sd1 += (double)A0.y + (double)A1.y + (double)A2.y + (double)A3.y
         + (double)A4.y + (double)A5.y + (double)A6.y + (double)A7.y;
    sd2 += (double)A0.z + (double)A1.z + (double)A2.z + (double)A3.z
         + (double)A4.z + (double)A5.z + (double)A6.z + (double)A7.z;
    sd3 += (double)A0.w + (double)A1.w + (double)A2.w + (double)A3.w
         + (double)A4.w + (double)A5.w + (double)A6.w + (double)A7.w;
    qd0 += (double)A0.x*A0.x + (double)A1.x*A1.x + (double)A2.x*A2.x + (double)A3.x*A3.x
         + (double)A4.x*A4.x + (double)A5.x*A5.x + (double)A6.x*A6.x + (double)A7.x*A7.x;
    qd1 += (double)A0.y*A0.y + (double)A1.y*A1.y + (double)A2.y*A2.y + (double)A3.y*A3.y
         + (double)A4.y*A4.y + (double)A5.y*A5.y + (double)A6.y*A6.y + (double)A7.y*A7.y;
    qd2 += (double)A0.z*A0.z + (double)A1.z*A1.z + (double)A2.z*A2.z + (double)A3.z*A3.z
         + (double)A4.z*A4.z + (double)A5.z*A5.z + (double)A6.z*A6.z + (double)A7.z*A7.z;
    qd3 += (double)A0.w*A0.w + (double)A1.w*A1.w + (double)A2.w*A2.w + (double)A3.w*A3.w
         + (double)A4.w*A4.w + (double)A5.w*A5.w + (double)A6.w*A6.w + (double)A7.w*A7.w;
    __syncthreads();
  }

  int c = cb * 4;
  sm.b.lsum[pg * 128 + c + 0] = sd0;  sm.b.lsq[pg * 128 + c + 0] = qd0;
  sm.b.lsum[pg * 128 + c + 1] = sd1;  sm.b.lsq[pg * 128 + c + 1] = qd1;
  sm.b.lsum[pg * 128 + c + 2] = sd2;  sm.b.lsq[pg * 128 + c + 2] = qd2;
  sm.b.lsum[pg * 128 + c + 3] = sd3;  sm.b.lsq[pg * 128 + c + 3] = qd3;
  __syncthreads();
  if (t < 128) {
    double S = 0, Q = 0;
    #pragma unroll
    for (int j = 0; j < 8; ++j) { S += sm.b.lsum[j * 128 + t]; Q += sm.b.lsq[j * 128 + t]; }
    atomicAdd(&gs[t], S);
    atomicAdd(&gq[t], Q);
  }
}

__global__ __launch_bounds__(256) void final2(const float* __restrict__ pts,
    const float* __restrict__ vcnt, const float* __restrict__ vsx,
    const float* __restrict__ vsy, const float* __restrict__ vsz,
    const unsigned int* __restrict__ voxloc, const unsigned int* __restrict__ bexc,
    const unsigned int* __restrict__ plist,
    const float* __restrict__ W0, const float* __restrict__ sc0,
    const float* __restrict__ sh0, const float* __restrict__ vmax,
    const float* __restrict__ W1, const float* __restrict__ sc1,
    const float* __restrict__ sh1, float* __restrict__ outp) {
  __shared__ float sf[STRETCH][12];
  __shared__ int   svid[STRETCH];
  __shared__ float sfeat[STRETCH][128];

  int t = threadIdx.x;
  int pg = t >> 5, cb = t & 31;
  unsigned int sbeg = blockIdx.x * STRETCH;

  TILE_STAGE(sbeg)
  TILE_GEMM()
  __syncthreads();

  int c = cb * 4;
  float4 s1v = *reinterpret_cast<const float4*>(sc1 + c);
  float4 h1v = *reinterpret_cast<const float4*>(sh1 + c);
  #define BNST(Aj, j)                                                        \
    { float4 P;                                                              \
      P.x = fmaxf(fmaf(Aj.x, s1v.x, h1v.x), 0.f);                            \
      P.y = fmaxf(fmaf(Aj.y, s1v.y, h1v.y), 0.f);                            \
      P.z = fmaxf(fmaf(Aj.z, s1v.z, h1v.z), 0.f);                            \
      P.w = fmaxf(fmaf(Aj.w, s1v.w, h1v.w), 0.f);                            \
      *reinterpret_cast<float4*>(&sfeat[pg * 8 + j][c]) = P; }
  BNST(A0, 0) BNST(A1, 1) BNST(A2, 2) BNST(A3, 3)
  BNST(A4, 4) BNST(A5, 5) BNST(A6, 6) BNST(A7, 7)
  #undef BNST
  __syncthreads();

  if (t < 128) {
    int curv = -1; float curm = 0.f;
    for (int i = 0; i < STRETCH; ++i) {
      int v = svid[i];
      if (v != curv) {
        if (curv >= 0) {
          unsigned int vstart = voxloc[curv] + bexc[curv >> 8];
          unsigned int n = (unsigned int)vcnt[curv];
          if (vstart >= sbeg && vstart + n <= sbeg + STRETCH)
            outp[(size_t)curv * 128 + t] = curm;
          else
            atomicMax((unsigned int*)&outp[(size_t)curv * 128 + t],
                      __float_as_uint(curm));
        }
        curv = v;
        curm = sfeat[i][t];
      } else {
        curm = fmaxf(curm, sfeat[i][t]);
      }
    }
    if (curv >= 0) {
      unsigned int vstart = voxloc[curv] + bexc[curv >> 8];
      unsigned int n = (unsigned int)vcnt[curv];
      if (vstart >= sbeg && vstart + n <= sbeg + STRETCH)
        outp[(size_t)curv * 128 + t] = curm;
      else
        atomicMax((unsigned int*)&outp[(size_t)curv * 128 + t],
                  __float_as_uint(curm));
    }
  }
}

extern "C" void kernel_launch(void* const* d_in, const int* in_sizes, int n_in,
                              void* d_out, int out_size, void* d_ws, size_t ws_size,
                              hipStream_t stream) {
  const float* pts = (const float*)d_in[0];
  const float* W0  = (const float*)d_in[1];
  const float* g0  = (const float*)d_in[2];
  const float* b0  = (const float*)d_in[3];
  const float* W1  = (const float*)d_in[4];
  const float* g1  = (const float*)d_in[5];
  const float* b1  = (const float*)d_in[6];

  // ws layout: one contiguous zeroed region up front (single memset)
  char* base = (char*)d_ws;
  double* stats = (double*)base;                       // 3072 B (zeroed)
  float*  fold  = (float*)(base + 3072);               // 1536 B
  float*  vcnt  = (float*)(base + 4608);               // zeroed
  float*  vsx   = vcnt + NVOX;
  float*  vsy   = vsx + NVOX;
  float*  vsz   = vsy + NVOX;
  unsigned int* cursor = (unsigned int*)(vsz + NVOX);  // zeroed
  size_t zbytes = 4608 + (size_t)5 * NVOX * 4;
  unsigned int* voxloc = cursor + NVOX;
  unsigned int* plist  = voxloc + NVOX;
  unsigned int* vsort  = plist + NPTS;
  unsigned int* bsum   = vsort + NPTS;
  unsigned int* bexc   = bsum + SCANB;
  double* gpart = (double*)(bexc + SCANB);             // GRAMB*65 dbl (33KB)
  float* vmax = (float*)(gpart + GRAMB * 65);          // NVOX*64 f32 (72MB)
  _Float16* Wf = (_Float16*)(vmax + (size_t)NVOX * 64);// 32KB
  _Float16* h1 = Wf + 32 * 64 * 8;                     // NPTS*128 fp16 (102MB)
  size_t need_fast = (size_t)((char*)h1 - base) + (size_t)NPTS * 128 * sizeof(_Float16);
  bool fast = ws_size >= need_fast;

  double* s1 = stats + 128, *q1 = stats + 256;
  float* sc0 = fold,       *sh0 = fold + 64;
  float* sc1 = fold + 128, *sh1 = fold + 256;

  hipMemsetAsync(base, 0, zbytes, stream);

  voxsum<<<NBLK, TPB, 0, stream>>>(pts, vcnt, vsx, vsy, vsz);
  scan1<<<SCANB, 256, 0, stream>>>(vcnt, voxloc, bsum);
  scan2<<<1, 64, 0, stream>>>(bsum, bexc);
  prep<<<SCANB, 256, 0, stream>>>(vcnt, voxloc, bexc, vmax, (float*)d_out);
  scatter<<<NBLK, TPB, 0, stream>>>(pts, voxloc, bexc, cursor, plist, vsort);
  bn0gram<<<GRAMB, 256, 0, stream>>>(pts, vcnt, vsx, vsy, vsz, gpart);
  bnfold0g<<<1, 128, 0, stream>>>(gpart, W0, g0, b0, sc0, sh0);
  vmax0_stretch<<<FBLK, TPB, 0, stream>>>(pts, vcnt, vsx, vsy, vsz, voxloc, bexc,
                                          plist, W0, sc0, sh0, vmax);
  if (fast) {
    wconv<<<64, 256, 0, stream>>>(W1, Wf);
    gemm1m<<<SBLK2, TPB, 0, stream>>>(pts, vcnt, vsx, vsy, vsz, plist,
                                      W0, sc0, sh0, vmax, Wf, s1, q1, h1);
    bnfold<<<1, 128, 0, stream>>>(s1, q1, g1, b1, sc1, sh1, 128);
    final_cheap<<<(FBLK + 3) / 4, 256, 0, stream>>>(vsort, voxloc, bexc, vcnt,
                                                    h1, sc1, sh1, (float*)d_out);
  } else {
    gemm1s_f32<<<SBLK2, TPB, 0, stream>>>(pts, vcnt, vsx, vsy, vsz, plist,
                                          W0, sc0, sh0, vmax, W1, s1, q1);
    bnfold<<<1, 128, 0, stream>>>(s1, q1, g1, b1, sc1, sh1, 128);
    final2<<<FBLK, TPB, 0, stream>>>(pts, vcnt, vsx, vsy, vsz, voxloc, bexc,
                                     plist, W0, sc0, sh0, vmax, W1, sc1, sh1,
                                     (float*)d_out);
  }
}